// Round 3
// baseline (2271.187 us; speedup 1.0000x reference)
//
#include <hip/hip_runtime.h>
#include <hip/hip_bf16.h>

#define BT 16384
#define NB 8192
#define DD 256
#define MARGIN 1e-4f

// ws layout (bytes)
#define WS_INV  0
#define WS_WSQ  (BT*4)            // 65536
#define WS_IDX  (WS_WSQ + NB*4)   // 98304
#define WS_CNT  (WS_IDX + BT*4)   // 163840
#define WS_LIST (WS_CNT + 64)     // 163904  (+65536 -> ~229KB total)

// ---------- kernel 1: row sum-of-squares (f64), store inv_norm or wsq ----------
__global__ void rownorm_kernel(const float* __restrict__ x, int rows,
                               float* __restrict__ out, int mode) {
    int row  = blockIdx.x * 4 + (threadIdx.x >> 6);
    int lane = threadIdx.x & 63;
    if (row >= rows) return;
    const float4 v = *reinterpret_cast<const float4*>(x + (size_t)row * DD + lane * 4);
    double s = (double)v.x * v.x + (double)v.y * v.y + (double)v.z * v.z + (double)v.w * v.w;
    #pragma unroll
    for (int off = 32; off; off >>= 1) s += __shfl_down(s, off, 64);
    if (lane == 0) {
        if (mode == 0) {
            double n = sqrt(s);
            if (n < 1e-12) n = 1e-12;
            out[row] = (float)(1.0 / n);
        } else {
            out[row] = (float)s;
        }
    }
}

// ---------- kernel 2: fused dot + argmin (f32), 64x64 chunk, 4x4 microtile ----------
__launch_bounds__(256, 1)
__global__ void argmin_kernel(const float* __restrict__ z,
                              const float* __restrict__ w,
                              const float* __restrict__ invn,
                              const float* __restrict__ wsq,
                              int* __restrict__ idx_out,
                              int* __restrict__ counter,
                              int* __restrict__ list) {
    __shared__ __align__(16) float zs[64][260];
    __shared__ __align__(16) float ws_[64][260];
    __shared__ float wsq_s[64];
    __shared__ float red_m1[2][64];
    __shared__ float red_m2[2][64];
    __shared__ int   red_i1[2][64];

    const int t    = threadIdx.x;
    const int wave = t >> 6;
    const int lane = t & 63;
    const int wy = wave >> 1, wx = wave & 1;   // 2x2 wave grid
    const int ly = lane >> 3, lx = lane & 7;
    const int r0 = blockIdx.x * 64;

    // stage 64 z rows into LDS, coalesced float4 (16 per thread)
    #pragma unroll
    for (int j = 0; j < 16; ++j) {
        int id = t + 256 * j;            // 0..4095
        int r = id >> 6, kq = id & 63;
        float4 v = *reinterpret_cast<const float4*>(z + (size_t)(r0 + r) * DD + kq * 4);
        *reinterpret_cast<float4*>(&zs[r][kq * 4]) = v;
    }

    int rloc[4]; float inv[4];
    #pragma unroll
    for (int i = 0; i < 4; ++i) {
        rloc[i] = wy * 32 + ly + 8 * i;
        inv[i]  = invn[r0 + rloc[i]];
    }
    int cloc[4];
    #pragma unroll
    for (int j = 0; j < 4; ++j) cloc[j] = wx * 32 + lx + 8 * j;

    float m1[4], m2[4]; int i1[4];
    #pragma unroll
    for (int i = 0; i < 4; ++i) { m1[i] = INFINITY; m2[i] = INFINITY; i1[i] = 0; }

    // prefetch chunk 0 of W (64 codes) into registers
    float4 pre[16];
    #pragma unroll
    for (int j = 0; j < 16; ++j) {
        int id = t + 256 * j;            // 0..4095
        int c = id >> 6, kq = id & 63;
        pre[j] = *reinterpret_cast<const float4*>(w + (size_t)c * DD + kq * 4);
    }
    float wsq_pre = (t < 64) ? wsq[t] : 0.f;

    for (int ch = 0; ch < 128; ++ch) {
        __syncthreads();                 // prev k-loop done; safe to overwrite ws_
        #pragma unroll
        for (int j = 0; j < 16; ++j) {
            int id = t + 256 * j;
            int c = id >> 6, kq = id & 63;
            *reinterpret_cast<float4*>(&ws_[c][kq * 4]) = pre[j];
        }
        if (t < 64) wsq_s[t] = wsq_pre;
        __syncthreads();

        // prefetch next chunk while computing (hide latency under the k-loop)
        if (ch < 127) {
            const float* wbase = w + (size_t)(ch + 1) * 64 * DD;
            #pragma unroll
            for (int j = 0; j < 16; ++j) {
                int id = t + 256 * j;
                int c = id >> 6, kq = id & 63;
                pre[j] = *reinterpret_cast<const float4*>(wbase + (size_t)c * DD + kq * 4);
            }
            if (t < 64) wsq_pre = wsq[(ch + 1) * 64 + t];
        }

        float acc[4][4];
        #pragma unroll
        for (int i = 0; i < 4; ++i)
            #pragma unroll
            for (int j = 0; j < 4; ++j) acc[i][j] = 0.f;

        #pragma unroll 4
        for (int k = 0; k < 256; k += 4) {
            float4 a[4], b[4];
            #pragma unroll
            for (int i = 0; i < 4; ++i)
                a[i] = *reinterpret_cast<const float4*>(&zs[rloc[i]][k]);
            #pragma unroll
            for (int j = 0; j < 4; ++j)
                b[j] = *reinterpret_cast<const float4*>(&ws_[cloc[j]][k]);
            #pragma unroll
            for (int i = 0; i < 4; ++i)
                #pragma unroll
                for (int j = 0; j < 4; ++j) {
                    acc[i][j] += a[i].x * b[j].x;
                    acc[i][j] += a[i].y * b[j].y;
                    acc[i][j] += a[i].z * b[j].z;
                    acc[i][j] += a[i].w * b[j].w;
                }
        }

        int nbase = ch * 64;
        #pragma unroll
        for (int j = 0; j < 4; ++j) {
            float wq = wsq_s[cloc[j]];
            int n = nbase + cloc[j];
            #pragma unroll
            for (int i = 0; i < 4; ++i) {
                float v = wq - 2.0f * inv[i] * acc[i][j];
                if (v < m1[i]) { m2[i] = m1[i]; m1[i] = v; i1[i] = n; }
                else if (v < m2[i]) m2[i] = v;
            }
        }
    }

    // reduce across lx lanes (bits 0..2); ties -> smaller index
    #pragma unroll
    for (int off = 1; off < 8; off <<= 1) {
        #pragma unroll
        for (int i = 0; i < 4; ++i) {
            float om1 = __shfl_xor(m1[i], off, 64);
            float om2 = __shfl_xor(m2[i], off, 64);
            int   oi1 = __shfl_xor(i1[i], off, 64);
            if (om1 < m1[i] || (om1 == m1[i] && oi1 < i1[i])) {
                m2[i] = fminf(m1[i], om2); m1[i] = om1; i1[i] = oi1;
            } else {
                m2[i] = fminf(om1, m2[i]);
            }
        }
    }
    if (lx == 0) {
        #pragma unroll
        for (int i = 0; i < 4; ++i) {
            red_m1[wx][rloc[i]] = m1[i];
            red_m2[wx][rloc[i]] = m2[i];
            red_i1[wx][rloc[i]] = i1[i];
        }
    }
    __syncthreads();
    if (t < 64) {
        float a1 = red_m1[0][t], a2 = red_m2[0][t]; int ai = red_i1[0][t];
        float b1 = red_m1[1][t], b2 = red_m2[1][t]; int bi = red_i1[1][t];
        float f1, f2; int fi;
        if (b1 < a1 || (b1 == a1 && bi < ai)) { f1 = b1; fi = bi; f2 = fminf(a1, b2); }
        else                                  { f1 = a1; fi = ai; f2 = fminf(b1, a2); }
        idx_out[r0 + t] = fi;
        if (f2 - f1 < MARGIN) {
            int p = atomicAdd(counter, 1);
            list[p] = r0 + t;
        }
    }
}

// ---------- kernel 3: exact f64 re-resolution for near-tie rows ----------
__global__ void refine_kernel(const float* __restrict__ z,
                              const float* __restrict__ w,
                              const int* __restrict__ counter,
                              const int* __restrict__ list,
                              int* __restrict__ idx_out) {
    __shared__ double zn_s[256];
    __shared__ double rv[256];
    __shared__ int    ri[256];
    const int t = threadIdx.x;
    const int cnt = *counter;
    for (int item = blockIdx.x; item < cnt; item += gridDim.x) {
        const int row = list[item];
        double zv = (double)z[(size_t)row * DD + t];
        __syncthreads();
        rv[t] = zv * zv;
        __syncthreads();
        for (int s = 128; s; s >>= 1) { if (t < s) rv[t] += rv[t + s]; __syncthreads(); }
        double norm = sqrt(rv[0]);
        if (norm < 1e-12) norm = 1e-12;
        __syncthreads();
        zn_s[t] = zv / norm;
        __syncthreads();
        double bv = INFINITY; int bi = 0;
        for (int n = t; n < NB; n += 256) {
            double dot = 0.0, wsqd = 0.0;
            const float* wr = w + (size_t)n * DD;
            for (int k = 0; k < DD; ++k) {
                double wv = (double)wr[k];
                dot  += zn_s[k] * wv;
                wsqd += wv * wv;
            }
            double dist = wsqd - 2.0 * dot;
            if (dist < bv) { bv = dist; bi = n; }
        }
        __syncthreads();
        rv[t] = bv; ri[t] = bi;
        __syncthreads();
        for (int s = 128; s; s >>= 1) {
            if (t < s) {
                if (rv[t + s] < rv[t] || (rv[t + s] == rv[t] && ri[t + s] < ri[t])) {
                    rv[t] = rv[t + s]; ri[t] = ri[t + s];
                }
            }
            __syncthreads();
        }
        if (t == 0) idx_out[row] = ri[0];
        __syncthreads();
    }
}

// ---------- kernel 4: gather z_q (f32) + idx (f32) ----------
__global__ void gather_kernel(const float* __restrict__ w,
                              const int* __restrict__ idx,
                              float* __restrict__ out) {
    const int t = threadIdx.x;
    const int blk = blockIdx.x;
    const int row = blk * 8 + (t >> 5);
    const int lane = t & 31;
    int n = idx[row];
    if ((unsigned)n >= (unsigned)NB) n = 0;   // defensive
    const float4* src = reinterpret_cast<const float4*>(w + (size_t)n * DD + lane * 8);
    float4 v0 = src[0], v1 = src[1];
    float4* dst = reinterpret_cast<float4*>(out + (size_t)row * DD + lane * 8);
    dst[0] = v0;
    dst[1] = v1;
    if (t < 8) {
        int r2 = blk * 8 + t;
        out[(size_t)BT * DD + r2] = (float)idx[r2];
    }
}

extern "C" void kernel_launch(void* const* d_in, const int* in_sizes, int n_in,
                              void* d_out, int out_size, void* d_ws, size_t ws_size,
                              hipStream_t stream) {
    const float* z = (const float*)d_in[0];
    const float* w = (const float*)d_in[1];
    float* out = (float*)d_out;
    char* ws = (char*)d_ws;
    float* inv  = (float*)(ws + WS_INV);
    float* wsq  = (float*)(ws + WS_WSQ);
    int*   idx  = (int*)(ws + WS_IDX);
    int*   cnt  = (int*)(ws + WS_CNT);
    int*   list = (int*)(ws + WS_LIST);

    hipMemsetAsync(cnt, 0, 4, stream);
    rownorm_kernel<<<BT / 4, 256, 0, stream>>>(z, BT, inv, 0);
    rownorm_kernel<<<NB / 4, 256, 0, stream>>>(w, NB, wsq, 1);
    argmin_kernel<<<BT / 64, 256, 0, stream>>>(z, w, inv, wsq, idx, cnt, list);
    refine_kernel<<<64, 256, 0, stream>>>(z, w, cnt, list, idx);
    gather_kernel<<<BT / 8, 256, 0, stream>>>(w, idx, out);
}

// Round 4
// 1289.562 us; speedup vs baseline: 1.7612x; 1.7612x over previous
//
#include <hip/hip_runtime.h>
#include <hip/hip_bf16.h>

#define BT 16384
#define NB 8192
#define DD 256
#define MARGIN 2e-4f

// ws layout (bytes)
#define WS_INV  0
#define WS_WSQ  (BT*4)
#define WS_IDX  (WS_WSQ + NB*4)
#define WS_CNT  (WS_IDX + BT*4)
#define WS_LIST (WS_CNT + 64)

typedef short bf16x8 __attribute__((ext_vector_type(8)));
typedef unsigned short u16x8 __attribute__((ext_vector_type(8)));
typedef float f32x16 __attribute__((ext_vector_type(16)));

// bf16 round-to-nearest-even from f32, bits in low 16
__device__ __forceinline__ unsigned int f2bf(float f) {
    unsigned int u = __float_as_uint(f);
    return (u + 0x7FFFu + ((u >> 16) & 1u)) >> 16;
}

// split 8 f32 into bf16 hi + bf16 lo (lo = bf16(x - f32(hi)))
__device__ __forceinline__ void split8(const float4 a, const float4 b, u16x8 &hv, u16x8 &lv) {
    float xs[8] = {a.x, a.y, a.z, a.w, b.x, b.y, b.z, b.w};
    #pragma unroll
    for (int i = 0; i < 8; ++i) {
        unsigned int h = f2bf(xs[i]);
        hv[i] = (unsigned short)h;
        lv[i] = (unsigned short)f2bf(xs[i] - __uint_as_float(h << 16));
    }
}

// ---------- kernel 1: row sum-of-squares (f64), store inv_norm or wsq ----------
__global__ void rownorm_kernel(const float* __restrict__ x, int rows,
                               float* __restrict__ out, int mode) {
    int row  = blockIdx.x * 4 + (threadIdx.x >> 6);
    int lane = threadIdx.x & 63;
    if (row >= rows) return;
    const float4 v = *reinterpret_cast<const float4*>(x + (size_t)row * DD + lane * 4);
    double s = (double)v.x * v.x + (double)v.y * v.y + (double)v.z * v.z + (double)v.w * v.w;
    #pragma unroll
    for (int off = 32; off; off >>= 1) s += __shfl_down(s, off, 64);
    if (lane == 0) {
        if (mode == 0) {
            double n = sqrt(s);
            if (n < 1e-12) n = 1e-12;
            out[row] = (float)(1.0 / n);
        } else {
            out[row] = (float)s;
        }
    }
}

// ---------- kernel 2: split-bf16 MFMA dot + argmin ----------
// 256 blocks x 256 thr. Block = 64 z-rows, loops 128 chunks of 64 codes.
// A (z) resident in LDS hi/lo bf16 full-K; B staged per chunk via reg prefetch.
// 4 waves in 2x2; one 32x32x16 MFMA tile per wave per chunk; 3 MFMAs per k-step.
__launch_bounds__(256, 1)
__global__ void argmin_mfma(const float* __restrict__ z,
                            const float* __restrict__ w,
                            const float* __restrict__ invn,
                            const float* __restrict__ wsq,
                            int* __restrict__ idx_out,
                            int* __restrict__ counter,
                            int* __restrict__ list) {
    __shared__ unsigned short Ahi[64][256];
    __shared__ unsigned short Alo[64][256];
    __shared__ unsigned short Bhi[64][256];
    __shared__ unsigned short Blo[64][256];
    __shared__ float wsq_s[64];
    __shared__ float red_m1[2][64];
    __shared__ float red_m2[2][64];
    __shared__ int   red_i1[2][64];

    const int t    = threadIdx.x;
    const int lane = t & 63;
    const int wv   = t >> 6;
    const int wy = wv >> 1, wx = wv & 1;
    const int l5 = lane >> 5, lq = lane & 31;
    const int r0 = blockIdx.x * 64;

    // ---- stage A (64 z-rows, full K) as hi/lo bf16 with slot-XOR swizzle ----
    {
        const int ar = t >> 2;                 // row 0..63
        const int sbase = (t & 3) * 8;         // slot base (each slot = 8 elems)
        const float* zr = z + (size_t)(r0 + ar) * DD + (t & 3) * 64;
        #pragma unroll
        for (int g = 0; g < 8; ++g) {
            float4 v0 = reinterpret_cast<const float4*>(zr)[2 * g];
            float4 v1 = reinterpret_cast<const float4*>(zr)[2 * g + 1];
            u16x8 hv, lv;
            split8(v0, v1, hv, lv);
            int slot = (sbase + g) ^ (ar & 7);
            *reinterpret_cast<u16x8*>(&Ahi[ar][slot * 8]) = hv;
            *reinterpret_cast<u16x8*>(&Alo[ar][slot * 8]) = lv;
        }
    }

    // hoisted per-row 2*inv for the 16 C-fragment rows this lane owns
    float twoinv[16];
    #pragma unroll
    for (int r = 0; r < 16; ++r)
        twoinv[r] = 2.0f * invn[r0 + wy * 32 + (r & 3) + 8 * (r >> 2) + 4 * l5];

    float m1[16], m2[16]; int i1[16];
    #pragma unroll
    for (int r = 0; r < 16; ++r) { m1[r] = INFINITY; m2[r] = INFINITY; i1[r] = 0; }

    // ---- prefetch B chunk 0 (64 codes x 256 dims f32) into registers ----
    const int cc = t >> 2;                     // code slot 0..63
    const int sbase = (t & 3) * 8;
    float4 pre[16];
    {
        const float* wb = w + (size_t)cc * DD + (t & 3) * 64;
        #pragma unroll
        for (int q = 0; q < 16; ++q) pre[q] = reinterpret_cast<const float4*>(wb)[q];
    }
    float wsq_pre = (t < 64) ? wsq[t] : 0.f;

    const int am = wy * 32 + lq;
    const int bn = wx * 32 + lq;
    const int sxor = lq & 7;

    for (int ch = 0; ch < 128; ++ch) {
        __syncthreads();                       // prior k-loop done reading B
        #pragma unroll
        for (int g = 0; g < 8; ++g) {
            u16x8 hv, lv;
            split8(pre[2 * g], pre[2 * g + 1], hv, lv);
            int slot = (sbase + g) ^ (cc & 7);
            *reinterpret_cast<u16x8*>(&Bhi[cc][slot * 8]) = hv;
            *reinterpret_cast<u16x8*>(&Blo[cc][slot * 8]) = lv;
        }
        if (t < 64) wsq_s[t] = wsq_pre;
        __syncthreads();

        if (ch < 127) {                        // prefetch next chunk
            const float* wb = w + (size_t)((ch + 1) * 64 + cc) * DD + (t & 3) * 64;
            #pragma unroll
            for (int q = 0; q < 16; ++q) pre[q] = reinterpret_cast<const float4*>(wb)[q];
            if (t < 64) wsq_pre = wsq[(ch + 1) * 64 + t];
        }

        f32x16 acc0, acc1;
        #pragma unroll
        for (int r = 0; r < 16; ++r) { acc0[r] = 0.f; acc1[r] = 0.f; }

        #pragma unroll
        for (int s = 0; s < 16; ++s) {
            const int sl = (2 * s + l5) ^ sxor;
            bf16x8 ah = *reinterpret_cast<const bf16x8*>(&Ahi[am][sl * 8]);
            bf16x8 al = *reinterpret_cast<const bf16x8*>(&Alo[am][sl * 8]);
            bf16x8 bh = *reinterpret_cast<const bf16x8*>(&Bhi[bn][sl * 8]);
            bf16x8 bl = *reinterpret_cast<const bf16x8*>(&Blo[bn][sl * 8]);
            acc0 = __builtin_amdgcn_mfma_f32_32x32x16_bf16(ah, bh, acc0, 0, 0, 0);
            acc1 = __builtin_amdgcn_mfma_f32_32x32x16_bf16(ah, bl, acc1, 0, 0, 0);
            acc0 = __builtin_amdgcn_mfma_f32_32x32x16_bf16(al, bh, acc0, 0, 0, 0);
        }

        const float wq = wsq_s[bn];
        const int nidx = ch * 64 + bn;
        #pragma unroll
        for (int r = 0; r < 16; ++r) {
            float v = wq - twoinv[r] * (acc0[r] + acc1[r]);
            if (v < m1[r]) { m2[r] = m1[r]; m1[r] = v; i1[r] = nidx; }
            else if (v < m2[r]) m2[r] = v;
        }
    }

    // ---- reduce across the 32 lanes (same l5 half) holding different codes ----
    #pragma unroll
    for (int off = 1; off < 32; off <<= 1) {
        #pragma unroll
        for (int r = 0; r < 16; ++r) {
            float om1 = __shfl_xor(m1[r], off, 64);
            float om2 = __shfl_xor(m2[r], off, 64);
            int   oi  = __shfl_xor(i1[r], off, 64);
            if (om1 < m1[r] || (om1 == m1[r] && oi < i1[r])) {
                m2[r] = fminf(m1[r], om2); m1[r] = om1; i1[r] = oi;
            } else {
                m2[r] = fminf(om1, m2[r]);
            }
        }
    }
    if (lq == 0) {
        #pragma unroll
        for (int r = 0; r < 16; ++r) {
            int ml = wy * 32 + (r & 3) + 8 * (r >> 2) + 4 * l5;
            red_m1[wx][ml] = m1[r];
            red_m2[wx][ml] = m2[r];
            red_i1[wx][ml] = i1[r];
        }
    }
    __syncthreads();
    if (t < 64) {
        float a1 = red_m1[0][t], a2 = red_m2[0][t]; int ai = red_i1[0][t];
        float b1 = red_m1[1][t], b2 = red_m2[1][t]; int bi = red_i1[1][t];
        float f1, f2; int fi;
        if (b1 < a1 || (b1 == a1 && bi < ai)) { f1 = b1; fi = bi; f2 = fminf(a1, b2); }
        else                                  { f1 = a1; fi = ai; f2 = fminf(b1, a2); }
        idx_out[r0 + t] = fi;
        if (f2 - f1 < MARGIN) {
            int p = atomicAdd(counter, 1);
            list[p] = r0 + t;
        }
    }
}

// ---------- kernel 3: exact f64 re-resolution for near-tie rows ----------
__global__ void refine_kernel(const float* __restrict__ z,
                              const float* __restrict__ w,
                              const int* __restrict__ counter,
                              const int* __restrict__ list,
                              int* __restrict__ idx_out) {
    __shared__ double zn_s[256];
    __shared__ double rv[256];
    __shared__ int    ri[256];
    const int t = threadIdx.x;
    const int cnt = *counter;
    for (int item = blockIdx.x; item < cnt; item += gridDim.x) {
        const int row = list[item];
        double zv = (double)z[(size_t)row * DD + t];
        __syncthreads();
        rv[t] = zv * zv;
        __syncthreads();
        for (int s = 128; s; s >>= 1) { if (t < s) rv[t] += rv[t + s]; __syncthreads(); }
        double norm = sqrt(rv[0]);
        if (norm < 1e-12) norm = 1e-12;
        __syncthreads();
        zn_s[t] = zv / norm;
        __syncthreads();
        double bv = INFINITY; int bi = 0;
        for (int n = t; n < NB; n += 256) {
            double dot = 0.0, wsqd = 0.0;
            const float* wr = w + (size_t)n * DD;
            for (int k = 0; k < DD; ++k) {
                double wv = (double)wr[k];
                dot  += zn_s[k] * wv;
                wsqd += wv * wv;
            }
            double dist = wsqd - 2.0 * dot;
            if (dist < bv) { bv = dist; bi = n; }
        }
        __syncthreads();
        rv[t] = bv; ri[t] = bi;
        __syncthreads();
        for (int s = 128; s; s >>= 1) {
            if (t < s) {
                if (rv[t + s] < rv[t] || (rv[t + s] == rv[t] && ri[t + s] < ri[t])) {
                    rv[t] = rv[t + s]; ri[t] = ri[t + s];
                }
            }
            __syncthreads();
        }
        if (t == 0) idx_out[row] = ri[0];
        __syncthreads();
    }
}

// ---------- kernel 4: gather z_q (f32) + idx (f32) ----------
__global__ void gather_kernel(const float* __restrict__ w,
                              const int* __restrict__ idx,
                              float* __restrict__ out) {
    const int t = threadIdx.x;
    const int blk = blockIdx.x;
    const int row = blk * 8 + (t >> 5);
    const int lane = t & 31;
    int n = idx[row];
    if ((unsigned)n >= (unsigned)NB) n = 0;   // defensive
    const float4* src = reinterpret_cast<const float4*>(w + (size_t)n * DD + lane * 8);
    float4 v0 = src[0], v1 = src[1];
    float4* dst = reinterpret_cast<float4*>(out + (size_t)row * DD + lane * 8);
    dst[0] = v0;
    dst[1] = v1;
    if (t < 8) {
        int r2 = blk * 8 + t;
        out[(size_t)BT * DD + r2] = (float)idx[r2];
    }
}

extern "C" void kernel_launch(void* const* d_in, const int* in_sizes, int n_in,
                              void* d_out, int out_size, void* d_ws, size_t ws_size,
                              hipStream_t stream) {
    const float* z = (const float*)d_in[0];
    const float* w = (const float*)d_in[1];
    float* out = (float*)d_out;
    char* ws = (char*)d_ws;
    float* inv  = (float*)(ws + WS_INV);
    float* wsq  = (float*)(ws + WS_WSQ);
    int*   idx  = (int*)(ws + WS_IDX);
    int*   cnt  = (int*)(ws + WS_CNT);
    int*   list = (int*)(ws + WS_LIST);

    hipMemsetAsync(cnt, 0, 4, stream);
    rownorm_kernel<<<BT / 4, 256, 0, stream>>>(z, BT, inv, 0);
    rownorm_kernel<<<NB / 4, 256, 0, stream>>>(w, NB, wsq, 1);
    argmin_mfma<<<BT / 64, 256, 0, stream>>>(z, w, inv, wsq, idx, cnt, list);
    refine_kernel<<<64, 256, 0, stream>>>(z, w, cnt, list, idx);
    gather_kernel<<<BT / 8, 256, 0, stream>>>(w, idx, out);
}

// Round 5
// 1169.994 us; speedup vs baseline: 1.9412x; 1.1022x over previous
//
#include <hip/hip_runtime.h>
#include <hip/hip_bf16.h>

#define BT 16384
#define NB 8192
#define DD 256
#define MARGIN 2e-4f
#define NCHUNK 128

// fast-path ws layout (bytes)
#define FW_WSQ   0
#define FW_IDX   (32*1024)
#define FW_CNT   (96*1024)
#define FW_LIST  (96*1024 + 256)
#define FW_WTILE (256*1024)
#define FW_NEED  ((size_t)(256*1024) + (size_t)NB*DD*2*2)   // 256KB + 8MB

// fallback ws layout (round-4, validated)
#define WS_INV  0
#define WS_WSQ  (BT*4)
#define WS_IDX  (WS_WSQ + NB*4)
#define WS_CNT  (WS_IDX + BT*4)
#define WS_LIST (WS_CNT + 64)

typedef short bf16x8 __attribute__((ext_vector_type(8)));
typedef unsigned short u16x8 __attribute__((ext_vector_type(8)));
typedef float f32x16 __attribute__((ext_vector_type(16)));

__device__ __forceinline__ unsigned int f2bf(float f) {
    unsigned int u = __float_as_uint(f);
    return (u + 0x7FFFu + ((u >> 16) & 1u)) >> 16;
}

__device__ __forceinline__ void split8(const float4 a, const float4 b, u16x8 &hv, u16x8 &lv) {
    float xs[8] = {a.x, a.y, a.z, a.w, b.x, b.y, b.z, b.w};
    #pragma unroll
    for (int i = 0; i < 8; ++i) {
        unsigned int h = f2bf(xs[i]);
        hv[i] = (unsigned short)h;
        lv[i] = (unsigned short)f2bf(xs[i] - __uint_as_float(h << 16));
    }
}

// ================= FAST PATH =================

// one-time: split W into bf16 hi/lo, slot-major tiled per 64-code chunk; also wsq
__global__ void wsplit_kernel(const float* __restrict__ w,
                              unsigned short* __restrict__ wtile,
                              float* __restrict__ wsq) {
    const int ch = blockIdx.x;         // 0..127
    const int t  = threadIdx.x;
    const int c  = t >> 2;             // code within chunk 0..63
    const int q  = t & 3;              // quarter of K
    const int n  = ch * 64 + c;
    const float* wr = w + (size_t)n * DD + q * 64;
    float4 v[16];
    #pragma unroll
    for (int i = 0; i < 16; ++i) v[i] = reinterpret_cast<const float4*>(wr)[i];
    double s = 0.0;
    #pragma unroll
    for (int i = 0; i < 16; ++i)
        s += (double)v[i].x*v[i].x + (double)v[i].y*v[i].y + (double)v[i].z*v[i].z + (double)v[i].w*v[i].w;
    s += __shfl_xor(s, 1, 64);
    s += __shfl_xor(s, 2, 64);
    if (q == 0) wsq[n] = (float)s;
    // tile layout: [ch][p][slot 0..31][code 0..63][8]
    unsigned short* base = wtile + (size_t)ch * 2 * 32 * 64 * 8;
    #pragma unroll
    for (int g = 0; g < 8; ++g) {
        u16x8 hv, lv;
        split8(v[2*g], v[2*g+1], hv, lv);
        const int slot = q * 8 + g;
        *reinterpret_cast<u16x8*>(base + ((size_t)slot*64 + c) * 8) = hv;
        *reinterpret_cast<u16x8*>(base + ((size_t)(32 + slot)*64 + c) * 8) = lv;
    }
}

// fused: normalize z (f64 norm), split-bf16 MFMA dots vs all codes, argmin+margin
__launch_bounds__(256, 1)
__global__ void argmin_fast(const float* __restrict__ z,
                            const unsigned short* __restrict__ wtile,
                            const float* __restrict__ wsq,
                            int* __restrict__ idx_out,
                            int* __restrict__ counter,
                            int* __restrict__ list) {
    __shared__ __align__(16) unsigned short Atile[2][32][64][8]; // 64 KB
    __shared__ __align__(16) unsigned short Btile[2][32][64][8]; // 64 KB
    __shared__ float wsq_s[64];
    __shared__ float red_m1[2][64];
    __shared__ float red_m2[2][64];
    __shared__ int   red_i1[2][64];

    const int t    = threadIdx.x;
    const int lane = t & 63;
    const int wv   = t >> 6;
    const int wy = wv >> 1, wx = wv & 1;
    const int l5 = lane >> 5, lq = lane & 31;
    const int r0 = blockIdx.x * 64;

    // ---- A stage (once): load 64 rows, f64 norm, scale, split, slot-major LDS
    {
        const int ar = t >> 2, q = t & 3;
        const float* zr = z + (size_t)(r0 + ar) * DD + q * 64;
        float4 v[16];
        #pragma unroll
        for (int i = 0; i < 16; ++i) v[i] = reinterpret_cast<const float4*>(zr)[i];
        double s = 0.0;
        #pragma unroll
        for (int i = 0; i < 16; ++i)
            s += (double)v[i].x*v[i].x + (double)v[i].y*v[i].y + (double)v[i].z*v[i].z + (double)v[i].w*v[i].w;
        s += __shfl_xor(s, 1, 64);
        s += __shfl_xor(s, 2, 64);
        double nrm = sqrt(s);
        if (nrm < 1e-12) nrm = 1e-12;
        const float inv = (float)(1.0 / nrm);
        #pragma unroll
        for (int g = 0; g < 8; ++g) {
            float4 a = v[2*g], b = v[2*g+1];
            a.x *= inv; a.y *= inv; a.z *= inv; a.w *= inv;
            b.x *= inv; b.y *= inv; b.z *= inv; b.w *= inv;
            u16x8 hv, lv;
            split8(a, b, hv, lv);
            const int slot = q * 8 + g;
            *reinterpret_cast<u16x8*>(&Atile[0][slot][ar][0]) = hv;
            *reinterpret_cast<u16x8*>(&Atile[1][slot][ar][0]) = lv;
        }
    }

    float m1[16], m2[16]; int i1[16];
    #pragma unroll
    for (int r = 0; r < 16; ++r) { m1[r] = INFINITY; m2[r] = INFINITY; i1[r] = 0; }

    // prefetch B chunk 0 (linear 64 KB copy, pre-split pre-tiled)
    const float4* wt = reinterpret_cast<const float4*>(wtile);
    float4 pre[16];
    #pragma unroll
    for (int j = 0; j < 16; ++j) pre[j] = wt[(size_t)j*256 + t];
    float wsq_pre = (t < 64) ? wsq[t] : 0.f;

    const int am = wy * 32 + lq;
    const int bn = wx * 32 + lq;

    for (int ch = 0; ch < NCHUNK; ++ch) {
        __syncthreads();               // prev k-loop done (and A-stage on ch=0)
        #pragma unroll
        for (int j = 0; j < 16; ++j)
            reinterpret_cast<float4*>(&Btile[0][0][0][0])[j*256 + t] = pre[j];
        if (t < 64) wsq_s[t] = wsq_pre;
        __syncthreads();

        if (ch < NCHUNK - 1) {         // prefetch next chunk under the k-loop
            #pragma unroll
            for (int j = 0; j < 16; ++j)
                pre[j] = wt[(size_t)(ch + 1)*4096 + j*256 + t];
            if (t < 64) wsq_pre = wsq[(ch + 1) * 64 + t];
        }

        f32x16 acc0, acc1;
        #pragma unroll
        for (int r = 0; r < 16; ++r) { acc0[r] = 0.f; acc1[r] = 0.f; }

        #pragma unroll
        for (int s = 0; s < 16; ++s) {
            const int sl = 2 * s + l5;
            bf16x8 ah = *reinterpret_cast<const bf16x8*>(&Atile[0][sl][am][0]);
            bf16x8 al = *reinterpret_cast<const bf16x8*>(&Atile[1][sl][am][0]);
            bf16x8 bh = *reinterpret_cast<const bf16x8*>(&Btile[0][sl][bn][0]);
            bf16x8 bl = *reinterpret_cast<const bf16x8*>(&Btile[1][sl][bn][0]);
            acc0 = __builtin_amdgcn_mfma_f32_32x32x16_bf16(ah, bh, acc0, 0, 0, 0);
            acc1 = __builtin_amdgcn_mfma_f32_32x32x16_bf16(ah, bl, acc1, 0, 0, 0);
            acc0 = __builtin_amdgcn_mfma_f32_32x32x16_bf16(al, bh, acc0, 0, 0, 0);
        }

        const float wq = wsq_s[bn];
        const int nidx = ch * 64 + bn;
        #pragma unroll
        for (int r = 0; r < 16; ++r) {
            float v = __builtin_fmaf(-2.0f, acc0[r] + acc1[r], wq);
            if (v < m1[r]) { m2[r] = m1[r]; m1[r] = v; i1[r] = nidx; }
            else if (v < m2[r]) m2[r] = v;
        }
    }

    // reduce across 32 code-lanes (ties -> smaller index)
    #pragma unroll
    for (int off = 1; off < 32; off <<= 1) {
        #pragma unroll
        for (int r = 0; r < 16; ++r) {
            float om1 = __shfl_xor(m1[r], off, 64);
            float om2 = __shfl_xor(m2[r], off, 64);
            int   oi  = __shfl_xor(i1[r], off, 64);
            if (om1 < m1[r] || (om1 == m1[r] && oi < i1[r])) {
                m2[r] = fminf(m1[r], om2); m1[r] = om1; i1[r] = oi;
            } else {
                m2[r] = fminf(om1, m2[r]);
            }
        }
    }
    if (lq == 0) {
        #pragma unroll
        for (int r = 0; r < 16; ++r) {
            int ml = wy * 32 + (r & 3) + 8 * (r >> 2) + 4 * l5;
            red_m1[wx][ml] = m1[r];
            red_m2[wx][ml] = m2[r];
            red_i1[wx][ml] = i1[r];
        }
    }
    __syncthreads();
    if (t < 64) {
        float a1 = red_m1[0][t], a2 = red_m2[0][t]; int ai = red_i1[0][t];
        float b1 = red_m1[1][t], b2 = red_m2[1][t]; int bi = red_i1[1][t];
        float f1, f2; int fi;
        if (b1 < a1 || (b1 == a1 && bi < ai)) { f1 = b1; fi = bi; f2 = fminf(a1, b2); }
        else                                  { f1 = a1; fi = ai; f2 = fminf(b1, a2); }
        idx_out[r0 + t] = fi;
        if (f2 - f1 < MARGIN) {
            int p = atomicAdd(counter, 1);
            list[p] = r0 + t;
        }
    }
}

// ================= SHARED (refine / gather) =================

__global__ void refine_kernel(const float* __restrict__ z,
                              const float* __restrict__ w,
                              const int* __restrict__ counter,
                              const int* __restrict__ list,
                              int* __restrict__ idx_out) {
    __shared__ double zn_s[256];
    __shared__ double rv[256];
    __shared__ int    ri[256];
    const int t = threadIdx.x;
    const int cnt = *counter;
    for (int item = blockIdx.x; item < cnt; item += gridDim.x) {
        const int row = list[item];
        double zv = (double)z[(size_t)row * DD + t];
        __syncthreads();
        rv[t] = zv * zv;
        __syncthreads();
        for (int s = 128; s; s >>= 1) { if (t < s) rv[t] += rv[t + s]; __syncthreads(); }
        double norm = sqrt(rv[0]);
        if (norm < 1e-12) norm = 1e-12;
        __syncthreads();
        zn_s[t] = zv / norm;
        __syncthreads();
        double bv = INFINITY; int bi = 0;
        for (int n = t; n < NB; n += 256) {
            double dot = 0.0, wsqd = 0.0;
            const float* wr = w + (size_t)n * DD;
            for (int k = 0; k < DD; ++k) {
                double wv = (double)wr[k];
                dot  += zn_s[k] * wv;
                wsqd += wv * wv;
            }
            double dist = wsqd - 2.0 * dot;
            if (dist < bv) { bv = dist; bi = n; }
        }
        __syncthreads();
        rv[t] = bv; ri[t] = bi;
        __syncthreads();
        for (int s = 128; s; s >>= 1) {
            if (t < s) {
                if (rv[t + s] < rv[t] || (rv[t + s] == rv[t] && ri[t + s] < ri[t])) {
                    rv[t] = rv[t + s]; ri[t] = ri[t + s];
                }
            }
            __syncthreads();
        }
        if (t == 0) idx_out[row] = ri[0];
        __syncthreads();
    }
}

__global__ void gather_kernel(const float* __restrict__ w,
                              const int* __restrict__ idx,
                              float* __restrict__ out) {
    const int t = threadIdx.x;
    const int blk = blockIdx.x;
    const int row = blk * 8 + (t >> 5);
    const int lane = t & 31;
    int n = idx[row];
    if ((unsigned)n >= (unsigned)NB) n = 0;
    const float4* src = reinterpret_cast<const float4*>(w + (size_t)n * DD + lane * 8);
    float4 v0 = src[0], v1 = src[1];
    float4* dst = reinterpret_cast<float4*>(out + (size_t)row * DD + lane * 8);
    dst[0] = v0;
    dst[1] = v1;
    if (t < 8) {
        int r2 = blk * 8 + t;
        out[(size_t)BT * DD + r2] = (float)idx[r2];
    }
}

// ================= FALLBACK PATH (round-4, validated) =================

__global__ void rownorm_kernel(const float* __restrict__ x, int rows,
                               float* __restrict__ out, int mode) {
    int row  = blockIdx.x * 4 + (threadIdx.x >> 6);
    int lane = threadIdx.x & 63;
    if (row >= rows) return;
    const float4 v = *reinterpret_cast<const float4*>(x + (size_t)row * DD + lane * 4);
    double s = (double)v.x * v.x + (double)v.y * v.y + (double)v.z * v.z + (double)v.w * v.w;
    #pragma unroll
    for (int off = 32; off; off >>= 1) s += __shfl_down(s, off, 64);
    if (lane == 0) {
        if (mode == 0) {
            double n = sqrt(s);
            if (n < 1e-12) n = 1e-12;
            out[row] = (float)(1.0 / n);
        } else {
            out[row] = (float)s;
        }
    }
}

__launch_bounds__(256, 1)
__global__ void argmin_mfma(const float* __restrict__ z,
                            const float* __restrict__ w,
                            const float* __restrict__ invn,
                            const float* __restrict__ wsq,
                            int* __restrict__ idx_out,
                            int* __restrict__ counter,
                            int* __restrict__ list) {
    __shared__ unsigned short Ahi[64][256];
    __shared__ unsigned short Alo[64][256];
    __shared__ unsigned short Bhi[64][256];
    __shared__ unsigned short Blo[64][256];
    __shared__ float wsq_s[64];
    __shared__ float red_m1[2][64];
    __shared__ float red_m2[2][64];
    __shared__ int   red_i1[2][64];

    const int t    = threadIdx.x;
    const int lane = t & 63;
    const int wv   = t >> 6;
    const int wy = wv >> 1, wx = wv & 1;
    const int l5 = lane >> 5, lq = lane & 31;
    const int r0 = blockIdx.x * 64;

    {
        const int ar = t >> 2;
        const int sbase = (t & 3) * 8;
        const float* zr = z + (size_t)(r0 + ar) * DD + (t & 3) * 64;
        #pragma unroll
        for (int g = 0; g < 8; ++g) {
            float4 v0 = reinterpret_cast<const float4*>(zr)[2 * g];
            float4 v1 = reinterpret_cast<const float4*>(zr)[2 * g + 1];
            u16x8 hv, lv;
            split8(v0, v1, hv, lv);
            int slot = (sbase + g) ^ (ar & 7);
            *reinterpret_cast<u16x8*>(&Ahi[ar][slot * 8]) = hv;
            *reinterpret_cast<u16x8*>(&Alo[ar][slot * 8]) = lv;
        }
    }

    float twoinv[16];
    #pragma unroll
    for (int r = 0; r < 16; ++r)
        twoinv[r] = 2.0f * invn[r0 + wy * 32 + (r & 3) + 8 * (r >> 2) + 4 * l5];

    float m1[16], m2[16]; int i1[16];
    #pragma unroll
    for (int r = 0; r < 16; ++r) { m1[r] = INFINITY; m2[r] = INFINITY; i1[r] = 0; }

    const int cc = t >> 2;
    const int sbase = (t & 3) * 8;
    float4 pre[16];
    {
        const float* wb = w + (size_t)cc * DD + (t & 3) * 64;
        #pragma unroll
        for (int q = 0; q < 16; ++q) pre[q] = reinterpret_cast<const float4*>(wb)[q];
    }
    float wsq_pre = (t < 64) ? wsq[t] : 0.f;

    const int am = wy * 32 + lq;
    const int bn = wx * 32 + lq;
    const int sxor = lq & 7;

    for (int ch = 0; ch < 128; ++ch) {
        __syncthreads();
        #pragma unroll
        for (int g = 0; g < 8; ++g) {
            u16x8 hv, lv;
            split8(pre[2 * g], pre[2 * g + 1], hv, lv);
            int slot = (sbase + g) ^ (cc & 7);
            *reinterpret_cast<u16x8*>(&Bhi[cc][slot * 8]) = hv;
            *reinterpret_cast<u16x8*>(&Blo[cc][slot * 8]) = lv;
        }
        if (t < 64) wsq_s[t] = wsq_pre;
        __syncthreads();

        if (ch < 127) {
            const float* wb = w + (size_t)((ch + 1) * 64 + cc) * DD + (t & 3) * 64;
            #pragma unroll
            for (int q = 0; q < 16; ++q) pre[q] = reinterpret_cast<const float4*>(wb)[q];
            if (t < 64) wsq_pre = wsq[(ch + 1) * 64 + t];
        }

        f32x16 acc0, acc1;
        #pragma unroll
        for (int r = 0; r < 16; ++r) { acc0[r] = 0.f; acc1[r] = 0.f; }

        #pragma unroll
        for (int s = 0; s < 16; ++s) {
            const int sl = (2 * s + l5) ^ sxor;
            bf16x8 ah = *reinterpret_cast<const bf16x8*>(&Ahi[am][sl * 8]);
            bf16x8 al = *reinterpret_cast<const bf16x8*>(&Alo[am][sl * 8]);
            bf16x8 bh = *reinterpret_cast<const bf16x8*>(&Bhi[bn][sl * 8]);
            bf16x8 bl = *reinterpret_cast<const bf16x8*>(&Blo[bn][sl * 8]);
            acc0 = __builtin_amdgcn_mfma_f32_32x32x16_bf16(ah, bh, acc0, 0, 0, 0);
            acc1 = __builtin_amdgcn_mfma_f32_32x32x16_bf16(ah, bl, acc1, 0, 0, 0);
            acc0 = __builtin_amdgcn_mfma_f32_32x32x16_bf16(al, bh, acc0, 0, 0, 0);
        }

        const float wq = wsq_s[bn];
        const int nidx = ch * 64 + bn;
        #pragma unroll
        for (int r = 0; r < 16; ++r) {
            float v = wq - twoinv[r] * (acc0[r] + acc1[r]);
            if (v < m1[r]) { m2[r] = m1[r]; m1[r] = v; i1[r] = nidx; }
            else if (v < m2[r]) m2[r] = v;
        }
    }

    #pragma unroll
    for (int off = 1; off < 32; off <<= 1) {
        #pragma unroll
        for (int r = 0; r < 16; ++r) {
            float om1 = __shfl_xor(m1[r], off, 64);
            float om2 = __shfl_xor(m2[r], off, 64);
            int   oi  = __shfl_xor(i1[r], off, 64);
            if (om1 < m1[r] || (om1 == m1[r] && oi < i1[r])) {
                m2[r] = fminf(m1[r], om2); m1[r] = om1; i1[r] = oi;
            } else {
                m2[r] = fminf(om1, m2[r]);
            }
        }
    }
    if (lq == 0) {
        #pragma unroll
        for (int r = 0; r < 16; ++r) {
            int ml = wy * 32 + (r & 3) + 8 * (r >> 2) + 4 * l5;
            red_m1[wx][ml] = m1[r];
            red_m2[wx][ml] = m2[r];
            red_i1[wx][ml] = i1[r];
        }
    }
    __syncthreads();
    if (t < 64) {
        float a1 = red_m1[0][t], a2 = red_m2[0][t]; int ai = red_i1[0][t];
        float b1 = red_m1[1][t], b2 = red_m2[1][t]; int bi = red_i1[1][t];
        float f1, f2; int fi;
        if (b1 < a1 || (b1 == a1 && bi < ai)) { f1 = b1; fi = bi; f2 = fminf(a1, b2); }
        else                                  { f1 = a1; fi = ai; f2 = fminf(b1, a2); }
        idx_out[r0 + t] = fi;
        if (f2 - f1 < MARGIN) {
            int p = atomicAdd(counter, 1);
            list[p] = r0 + t;
        }
    }
}

extern "C" void kernel_launch(void* const* d_in, const int* in_sizes, int n_in,
                              void* d_out, int out_size, void* d_ws, size_t ws_size,
                              hipStream_t stream) {
    const float* z = (const float*)d_in[0];
    const float* w = (const float*)d_in[1];
    float* out = (float*)d_out;
    char* ws = (char*)d_ws;

    if (ws_size >= FW_NEED) {
        float* wsq  = (float*)(ws + FW_WSQ);
        int*   idx  = (int*)(ws + FW_IDX);
        int*   cnt  = (int*)(ws + FW_CNT);
        int*   list = (int*)(ws + FW_LIST);
        unsigned short* wtile = (unsigned short*)(ws + FW_WTILE);

        hipMemsetAsync(cnt, 0, 4, stream);
        wsplit_kernel<<<NCHUNK, 256, 0, stream>>>(w, wtile, wsq);
        argmin_fast<<<BT / 64, 256, 0, stream>>>(z, wtile, wsq, idx, cnt, list);
        refine_kernel<<<128, 256, 0, stream>>>(z, w, cnt, list, idx);
        gather_kernel<<<BT / 8, 256, 0, stream>>>(w, idx, out);
    } else {
        float* inv  = (float*)(ws + WS_INV);
        float* wsq  = (float*)(ws + WS_WSQ);
        int*   idx  = (int*)(ws + WS_IDX);
        int*   cnt  = (int*)(ws + WS_CNT);
        int*   list = (int*)(ws + WS_LIST);

        hipMemsetAsync(cnt, 0, 4, stream);
        rownorm_kernel<<<BT / 4, 256, 0, stream>>>(z, BT, inv, 0);
        rownorm_kernel<<<NB / 4, 256, 0, stream>>>(w, NB, wsq, 1);
        argmin_mfma<<<BT / 64, 256, 0, stream>>>(z, w, inv, wsq, idx, cnt, list);
        refine_kernel<<<64, 256, 0, stream>>>(z, w, cnt, list, idx);
        gather_kernel<<<BT / 8, 256, 0, stream>>>(w, idx, out);
    }
}

// Round 6
// 785.792 us; speedup vs baseline: 2.8903x; 1.4889x over previous
//
#include <hip/hip_runtime.h>
#include <hip/hip_bf16.h>

#define BT 16384
#define NB 8192
#define DD 256
#define MARGIN 2e-4f

typedef short bf16x8 __attribute__((ext_vector_type(8)));
typedef unsigned short u16x8 __attribute__((ext_vector_type(8)));
typedef float f32x16 __attribute__((ext_vector_type(16)));
typedef __attribute__((address_space(1))) unsigned int gu32;
typedef __attribute__((address_space(3))) unsigned int lu32;

// ---- fast-path ws layout (bytes): wtile 8MB + partials + idx + cnt + list ----
#define W2_WTILE 0
#define W2_PM1   (8*1024*1024)
#define W2_PM2   (W2_PM1 + 2*BT*4)
#define W2_PI1   (W2_PM2 + 2*BT*4)
#define W2_IDX   (W2_PI1 + 2*BT*4)
#define W2_CNT   (W2_IDX + BT*4)
#define W2_LIST  (W2_CNT + 256)
#define W2_NEED  ((size_t)(W2_LIST + BT*4))

// ---- fallback ws layout (round-4, validated) ----
#define WS_INV  0
#define WS_WSQ  (BT*4)
#define WS_IDX  (WS_WSQ + NB*4)
#define WS_CNT  (WS_IDX + BT*4)
#define WS_LIST (WS_CNT + 64)

__device__ __forceinline__ unsigned int f2bf(float f) {
    unsigned int u = __float_as_uint(f);
    return (u + 0x7FFFu + ((u >> 16) & 1u)) >> 16;
}

__device__ __forceinline__ void split8(const float4 a, const float4 b, u16x8 &hv, u16x8 &lv) {
    float xs[8] = {a.x, a.y, a.z, a.w, b.x, b.y, b.z, b.w};
    #pragma unroll
    for (int i = 0; i < 8; ++i) {
        unsigned int h = f2bf(xs[i]);
        hv[i] = (unsigned short)h;
        lv[i] = (unsigned short)f2bf(xs[i] - __uint_as_float(h << 16));
    }
}

// ================= FAST PATH =================

// Pre-split W: [ch 128][p 2][slot 32][code 64][8] bf16 (hi plane p=0, lo p=1)
__global__ void wsplit_kernel(const float* __restrict__ w,
                              unsigned short* __restrict__ wtile) {
    const int ch = blockIdx.x;         // 0..127
    const int t  = threadIdx.x;
    const int c  = t >> 2;             // code within chunk
    const int q  = t & 3;              // K-quarter
    const float* wr = w + (size_t)(ch * 64 + c) * DD + q * 64;
    unsigned short* base = wtile + (size_t)ch * 32768;
    #pragma unroll
    for (int g = 0; g < 8; ++g) {
        float4 v0 = reinterpret_cast<const float4*>(wr)[2 * g];
        float4 v1 = reinterpret_cast<const float4*>(wr)[2 * g + 1];
        u16x8 hv, lv;
        split8(v0, v1, hv, lv);
        const int slot = q * 8 + g;
        *reinterpret_cast<u16x8*>(base + ((size_t)slot * 64 + c) * 8) = hv;
        *reinterpret_cast<u16x8*>(base + ((size_t)(32 + slot) * 64 + c) * 8) = lv;
    }
}

// Pre-split z: normalize (f64) + split, MFMA-fragment-major:
// zt[(rt*16+s)*64 + l] (16B) = row rt*32+(l&31), k = s*16+(l>>5)*8 .. +8
// hi plane at zt[0..524287], lo plane at +524288 (lives in d_out's z_q region)
__global__ void zsplit_kernel(const float* __restrict__ z,
                              u16x8* __restrict__ zt) {
    __shared__ float inv_s[32];
    const int t = threadIdx.x;
    const int rt = blockIdx.x;         // 0..511 (32 rows each)
    {   // phase 1: row norms (8 threads per row)
        const int rl = t >> 3, sub = t & 7;
        const float4* zr = reinterpret_cast<const float4*>(
            z + (size_t)(rt * 32 + rl) * DD + sub * 32);
        double s = 0.0;
        #pragma unroll
        for (int i = 0; i < 8; ++i) {
            float4 v = zr[i];
            s += (double)v.x*v.x + (double)v.y*v.y + (double)v.z*v.z + (double)v.w*v.w;
        }
        s += __shfl_xor(s, 1, 64);
        s += __shfl_xor(s, 2, 64);
        s += __shfl_xor(s, 4, 64);
        if (sub == 0) {
            double n = sqrt(s);
            if (n < 1e-12) n = 1e-12;
            inv_s[rl] = (float)(1.0 / n);
        }
    }
    __syncthreads();
    const int sg = t >> 6, l = t & 63;
    const float inv = inv_s[l & 31];
    const int row = rt * 32 + (l & 31);
    #pragma unroll
    for (int si = 0; si < 4; ++si) {
        const int s = sg * 4 + si;
        const int k0 = s * 16 + (l >> 5) * 8;
        float4 a = *reinterpret_cast<const float4*>(z + (size_t)row * DD + k0);
        float4 b = *reinterpret_cast<const float4*>(z + (size_t)row * DD + k0 + 4);
        a.x *= inv; a.y *= inv; a.z *= inv; a.w *= inv;
        b.x *= inv; b.y *= inv; b.z *= inv; b.w *= inv;
        u16x8 hv, lv;
        split8(a, b, hv, lv);
        const size_t o = ((size_t)rt * 16 + s) * 64 + l;
        zt[o] = hv;
        zt[524288 + o] = lv;
    }
}

// Fused MFMA argmin: 512 blocks = 256 rowblocks(64 rows) x 2 code-halves.
// A in registers (hi+lo), B double-buffered via global_load_lds, counted vmcnt.
__launch_bounds__(256, 1)
__global__ void argmin2(const u16x8* __restrict__ zt,
                        const unsigned short* __restrict__ wtile,
                        float* __restrict__ pm1,
                        float* __restrict__ pm2,
                        int* __restrict__ pi1) {
    __shared__ __align__(16) unsigned short Bbuf[2][2][32][64][8]; // 128 KB
    __shared__ float red_m1[2][64];
    __shared__ float red_m2[2][64];
    __shared__ int   red_i1[2][64];

    const int t = threadIdx.x, lane = t & 63, wv = t >> 6;
    const int wy = wv >> 1, wx = wv & 1;
    const int l5 = lane >> 5, lq = lane & 31;
    const int b = blockIdx.x;
    const int xcd  = b & 7;
    const int half = xcd & 1;                  // XCD parity -> L2-resident 4MB half
    const int rb   = (b >> 3) * 4 + (xcd >> 1); // 0..255
    const int r0   = rb * 64;
    const int rt   = rb * 2 + wy;

    // ---- A-frags into registers: 16 ksteps x (hi,lo) ----
    const bf16x8* zhi = reinterpret_cast<const bf16x8*>(zt);
    bf16x8 ah[16], al[16];
    #pragma unroll
    for (int s = 0; s < 16; ++s) {
        const size_t o = ((size_t)rt * 16 + s) * 64 + lane;
        ah[s] = zhi[o];
        al[s] = zhi[524288 + o];
    }

    float m1[16], m2[16]; int i1[16];
    #pragma unroll
    for (int r = 0; r < 16; ++r) { m1[r] = INFINITY; m2[r] = INFINITY; i1[r] = 0; }

    const unsigned short* wsrc = wtile + (size_t)half * 2097152 + (size_t)t * 8;
    unsigned short* dst0 = &Bbuf[0][0][0][0][0] + (size_t)t * 8;
    unsigned short* dst1 = &Bbuf[1][0][0][0][0] + (size_t)t * 8;

    // prologue: stage chunk 0 into buf 0
    {
        const unsigned short* src = wsrc;
        #pragma unroll
        for (int i = 0; i < 16; ++i)
            __builtin_amdgcn_global_load_lds((gu32*)(src + i * 2048),
                                             (lu32*)(dst0 + i * 2048), 16, 0, 0);
    }

    const int bn = wx * 32 + lq;
    int cur = 0;
    for (int ch = 0; ch < 64; ++ch) {
        if (ch < 63) {                 // stage next chunk into other buffer
            const unsigned short* src = wsrc + (size_t)(ch + 1) * 32768;
            unsigned short* dst = cur ? dst0 : dst1;
            #pragma unroll
            for (int i = 0; i < 16; ++i)
                __builtin_amdgcn_global_load_lds((gu32*)(src + i * 2048),
                                                 (lu32*)(dst + i * 2048), 16, 0, 0);
            asm volatile("s_waitcnt vmcnt(16)" ::: "memory");
        } else {
            asm volatile("s_waitcnt vmcnt(0)" ::: "memory");
        }
        __builtin_amdgcn_s_barrier();
        __builtin_amdgcn_sched_barrier(0);

        f32x16 acc0, acc1;
        #pragma unroll
        for (int r = 0; r < 16; ++r) { acc0[r] = 0.f; acc1[r] = 0.f; }

        #pragma unroll
        for (int s = 0; s < 16; ++s) {
            const int sl = 2 * s + l5;
            bf16x8 bh = *reinterpret_cast<const bf16x8*>(&Bbuf[cur][0][sl][bn][0]);
            bf16x8 bl = *reinterpret_cast<const bf16x8*>(&Bbuf[cur][1][sl][bn][0]);
            acc0 = __builtin_amdgcn_mfma_f32_32x32x16_bf16(ah[s], bh, acc0, 0, 0, 0);
            acc1 = __builtin_amdgcn_mfma_f32_32x32x16_bf16(ah[s], bl, acc1, 0, 0, 0);
            acc0 = __builtin_amdgcn_mfma_f32_32x32x16_bf16(al[s], bh, acc0, 0, 0, 0);
        }

        const int nidx = half * 4096 + ch * 64 + bn;   // global code id
        #pragma unroll
        for (int r = 0; r < 16; ++r) {
            float v = -2.0f * (acc0[r] + acc1[r]);     // ||w||^2 == 1: rank by -2dot
            if (v < m1[r]) { m2[r] = m1[r]; m1[r] = v; i1[r] = nidx; }
            else if (v < m2[r]) m2[r] = v;
        }

        __builtin_amdgcn_sched_barrier(0);
        __builtin_amdgcn_s_barrier();   // all waves done reading Bbuf[cur]
        cur ^= 1;
    }

    // reduce across 32 code-lanes (ties -> smaller index)
    #pragma unroll
    for (int off = 1; off < 32; off <<= 1) {
        #pragma unroll
        for (int r = 0; r < 16; ++r) {
            float om1 = __shfl_xor(m1[r], off, 64);
            float om2 = __shfl_xor(m2[r], off, 64);
            int   oi  = __shfl_xor(i1[r], off, 64);
            if (om1 < m1[r] || (om1 == m1[r] && oi < i1[r])) {
                m2[r] = fminf(m1[r], om2); m1[r] = om1; i1[r] = oi;
            } else {
                m2[r] = fminf(om1, m2[r]);
            }
        }
    }
    if (lq == 0) {
        #pragma unroll
        for (int r = 0; r < 16; ++r) {
            int ml = wy * 32 + (r & 3) + 8 * (r >> 2) + 4 * l5;
            red_m1[wx][ml] = m1[r];
            red_m2[wx][ml] = m2[r];
            red_i1[wx][ml] = i1[r];
        }
    }
    __syncthreads();
    if (t < 64) {
        float a1 = red_m1[0][t], a2 = red_m2[0][t]; int ai = red_i1[0][t];
        float b1 = red_m1[1][t], b2 = red_m2[1][t]; int bi = red_i1[1][t];
        float f1, f2; int fi;
        if (b1 < a1 || (b1 == a1 && bi < ai)) { f1 = b1; fi = bi; f2 = fminf(a1, b2); }
        else                                  { f1 = a1; fi = ai; f2 = fminf(b1, a2); }
        pm1[half * BT + r0 + t] = f1;
        pm2[half * BT + r0 + t] = f2;
        pi1[half * BT + r0 + t] = fi;
    }
}

// merge the two code-halves per row; flag near-ties for refine
__global__ void merge_kernel(const float* __restrict__ pm1,
                             const float* __restrict__ pm2,
                             const int* __restrict__ pi1,
                             int* __restrict__ idx_out,
                             int* __restrict__ counter,
                             int* __restrict__ list) {
    const int r = blockIdx.x * 256 + threadIdx.x;
    float a1 = pm1[r], a2 = pm2[r]; int ai = pi1[r];
    float b1 = pm1[BT + r], b2 = pm2[BT + r]; int bi = pi1[BT + r];
    float f1, f2; int fi;
    if (b1 < a1 || (b1 == a1 && bi < ai)) { f1 = b1; fi = bi; f2 = fminf(a1, b2); }
    else                                  { f1 = a1; fi = ai; f2 = fminf(b1, a2); }
    idx_out[r] = fi;
    if (f2 - f1 < MARGIN) {
        int p = atomicAdd(counter, 1);
        list[p] = r;
    }
}

// ================= SHARED (refine / gather) =================

__global__ void refine_kernel(const float* __restrict__ z,
                              const float* __restrict__ w,
                              const int* __restrict__ counter,
                              const int* __restrict__ list,
                              int* __restrict__ idx_out) {
    __shared__ double zn_s[256];
    __shared__ double rv[256];
    __shared__ int    ri[256];
    const int t = threadIdx.x;
    const int cnt = *counter;
    for (int item = blockIdx.x; item < cnt; item += gridDim.x) {
        const int row = list[item];
        double zv = (double)z[(size_t)row * DD + t];
        __syncthreads();
        rv[t] = zv * zv;
        __syncthreads();
        for (int s = 128; s; s >>= 1) { if (t < s) rv[t] += rv[t + s]; __syncthreads(); }
        double norm = sqrt(rv[0]);
        if (norm < 1e-12) norm = 1e-12;
        __syncthreads();
        zn_s[t] = zv / norm;
        __syncthreads();
        double bv = INFINITY; int bi = 0;
        for (int n = t; n < NB; n += 256) {
            double dot = 0.0, wsqd = 0.0;
            const float* wr = w + (size_t)n * DD;
            for (int k = 0; k < DD; ++k) {
                double wv = (double)wr[k];
                dot  += zn_s[k] * wv;
                wsqd += wv * wv;
            }
            double dist = wsqd - 2.0 * dot;
            if (dist < bv) { bv = dist; bi = n; }
        }
        __syncthreads();
        rv[t] = bv; ri[t] = bi;
        __syncthreads();
        for (int s = 128; s; s >>= 1) {
            if (t < s) {
                if (rv[t + s] < rv[t] || (rv[t + s] == rv[t] && ri[t + s] < ri[t])) {
                    rv[t] = rv[t + s]; ri[t] = ri[t + s];
                }
            }
            __syncthreads();
        }
        if (t == 0) idx_out[row] = ri[0];
        __syncthreads();
    }
}

__global__ void gather_kernel(const float* __restrict__ w,
                              const int* __restrict__ idx,
                              float* __restrict__ out) {
    const int t = threadIdx.x;
    const int blk = blockIdx.x;
    const int row = blk * 8 + (t >> 5);
    const int lane = t & 31;
    int n = idx[row];
    if ((unsigned)n >= (unsigned)NB) n = 0;
    const float4* src = reinterpret_cast<const float4*>(w + (size_t)n * DD + lane * 8);
    float4 v0 = src[0], v1 = src[1];
    float4* dst = reinterpret_cast<float4*>(out + (size_t)row * DD + lane * 8);
    dst[0] = v0;
    dst[1] = v1;
    if (t < 8) {
        int r2 = blk * 8 + t;
        out[(size_t)BT * DD + r2] = (float)idx[r2];
    }
}

// ================= FALLBACK (round-4, validated) =================

__global__ void rownorm_kernel(const float* __restrict__ x, int rows,
                               float* __restrict__ out, int mode) {
    int row  = blockIdx.x * 4 + (threadIdx.x >> 6);
    int lane = threadIdx.x & 63;
    if (row >= rows) return;
    const float4 v = *reinterpret_cast<const float4*>(x + (size_t)row * DD + lane * 4);
    double s = (double)v.x * v.x + (double)v.y * v.y + (double)v.z * v.z + (double)v.w * v.w;
    #pragma unroll
    for (int off = 32; off; off >>= 1) s += __shfl_down(s, off, 64);
    if (lane == 0) {
        if (mode == 0) {
            double n = sqrt(s);
            if (n < 1e-12) n = 1e-12;
            out[row] = (float)(1.0 / n);
        } else {
            out[row] = (float)s;
        }
    }
}

__launch_bounds__(256, 1)
__global__ void argmin_mfma(const float* __restrict__ z,
                            const float* __restrict__ w,
                            const float* __restrict__ invn,
                            const float* __restrict__ wsq,
                            int* __restrict__ idx_out,
                            int* __restrict__ counter,
                            int* __restrict__ list) {
    __shared__ unsigned short Ahi[64][256];
    __shared__ unsigned short Alo[64][256];
    __shared__ unsigned short Bhi[64][256];
    __shared__ unsigned short Blo[64][256];
    __shared__ float wsq_s[64];
    __shared__ float red_m1[2][64];
    __shared__ float red_m2[2][64];
    __shared__ int   red_i1[2][64];

    const int t    = threadIdx.x;
    const int lane = t & 63;
    const int wv   = t >> 6;
    const int wy = wv >> 1, wx = wv & 1;
    const int l5 = lane >> 5, lq = lane & 31;
    const int r0 = blockIdx.x * 64;

    {
        const int ar = t >> 2;
        const int sbase = (t & 3) * 8;
        const float* zr = z + (size_t)(r0 + ar) * DD + (t & 3) * 64;
        #pragma unroll
        for (int g = 0; g < 8; ++g) {
            float4 v0 = reinterpret_cast<const float4*>(zr)[2 * g];
            float4 v1 = reinterpret_cast<const float4*>(zr)[2 * g + 1];
            u16x8 hv, lv;
            split8(v0, v1, hv, lv);
            int slot = (sbase + g) ^ (ar & 7);
            *reinterpret_cast<u16x8*>(&Ahi[ar][slot * 8]) = hv;
            *reinterpret_cast<u16x8*>(&Alo[ar][slot * 8]) = lv;
        }
    }

    float twoinv[16];
    #pragma unroll
    for (int r = 0; r < 16; ++r)
        twoinv[r] = 2.0f * invn[r0 + wy * 32 + (r & 3) + 8 * (r >> 2) + 4 * l5];

    float m1[16], m2[16]; int i1[16];
    #pragma unroll
    for (int r = 0; r < 16; ++r) { m1[r] = INFINITY; m2[r] = INFINITY; i1[r] = 0; }

    const int cc = t >> 2;
    const int sbase = (t & 3) * 8;
    float4 pre[16];
    {
        const float* wb = w + (size_t)cc * DD + (t & 3) * 64;
        #pragma unroll
        for (int q = 0; q < 16; ++q) pre[q] = reinterpret_cast<const float4*>(wb)[q];
    }
    float wsq_pre = (t < 64) ? wsq[t] : 0.f;

    const int am = wy * 32 + lq;
    const int bn = wx * 32 + lq;
    const int sxor = lq & 7;

    for (int ch = 0; ch < 128; ++ch) {
        __syncthreads();
        #pragma unroll
        for (int g = 0; g < 8; ++g) {
            u16x8 hv, lv;
            split8(pre[2 * g], pre[2 * g + 1], hv, lv);
            int slot = (sbase + g) ^ (cc & 7);
            *reinterpret_cast<u16x8*>(&Bhi[cc][slot * 8]) = hv;
            *reinterpret_cast<u16x8*>(&Blo[cc][slot * 8]) = lv;
        }
        if (t < 64) wsq_s[t] = wsq_pre;
        __syncthreads();

        if (ch < 127) {
            const float* wb = w + (size_t)((ch + 1) * 64 + cc) * DD + (t & 3) * 64;
            #pragma unroll
            for (int q = 0; q < 16; ++q) pre[q] = reinterpret_cast<const float4*>(wb)[q];
            if (t < 64) wsq_pre = wsq[(ch + 1) * 64 + t];
        }

        f32x16 acc0, acc1;
        #pragma unroll
        for (int r = 0; r < 16; ++r) { acc0[r] = 0.f; acc1[r] = 0.f; }

        #pragma unroll
        for (int s = 0; s < 16; ++s) {
            const int sl = (2 * s + l5) ^ sxor;
            bf16x8 ah = *reinterpret_cast<const bf16x8*>(&Ahi[am][sl * 8]);
            bf16x8 al = *reinterpret_cast<const bf16x8*>(&Alo[am][sl * 8]);
            bf16x8 bh = *reinterpret_cast<const bf16x8*>(&Bhi[bn][sl * 8]);
            bf16x8 bl = *reinterpret_cast<const bf16x8*>(&Blo[bn][sl * 8]);
            acc0 = __builtin_amdgcn_mfma_f32_32x32x16_bf16(ah, bh, acc0, 0, 0, 0);
            acc1 = __builtin_amdgcn_mfma_f32_32x32x16_bf16(ah, bl, acc1, 0, 0, 0);
            acc0 = __builtin_amdgcn_mfma_f32_32x32x16_bf16(al, bh, acc0, 0, 0, 0);
        }

        const float wq = wsq_s[bn];
        const int nidx = ch * 64 + bn;
        #pragma unroll
        for (int r = 0; r < 16; ++r) {
            float v = wq - twoinv[r] * (acc0[r] + acc1[r]);
            if (v < m1[r]) { m2[r] = m1[r]; m1[r] = v; i1[r] = nidx; }
            else if (v < m2[r]) m2[r] = v;
        }
    }

    #pragma unroll
    for (int off = 1; off < 32; off <<= 1) {
        #pragma unroll
        for (int r = 0; r < 16; ++r) {
            float om1 = __shfl_xor(m1[r], off, 64);
            float om2 = __shfl_xor(m2[r], off, 64);
            int   oi  = __shfl_xor(i1[r], off, 64);
            if (om1 < m1[r] || (om1 == m1[r] && oi < i1[r])) {
                m2[r] = fminf(m1[r], om2); m1[r] = om1; i1[r] = oi;
            } else {
                m2[r] = fminf(om1, m2[r]);
            }
        }
    }
    if (lq == 0) {
        #pragma unroll
        for (int r = 0; r < 16; ++r) {
            int ml = wy * 32 + (r & 3) + 8 * (r >> 2) + 4 * l5;
            red_m1[wx][ml] = m1[r];
            red_m2[wx][ml] = m2[r];
            red_i1[wx][ml] = i1[r];
        }
    }
    __syncthreads();
    if (t < 64) {
        float a1 = red_m1[0][t], a2 = red_m2[0][t]; int ai = red_i1[0][t];
        float b1 = red_m1[1][t], b2 = red_m2[1][t]; int bi = red_i1[1][t];
        float f1, f2; int fi;
        if (b1 < a1 || (b1 == a1 && bi < ai)) { f1 = b1; fi = bi; f2 = fminf(a1, b2); }
        else                                  { f1 = a1; fi = ai; f2 = fminf(b1, a2); }
        idx_out[r0 + t] = fi;
        if (f2 - f1 < MARGIN) {
            int p = atomicAdd(counter, 1);
            list[p] = r0 + t;
        }
    }
}

extern "C" void kernel_launch(void* const* d_in, const int* in_sizes, int n_in,
                              void* d_out, int out_size, void* d_ws, size_t ws_size,
                              hipStream_t stream) {
    const float* z = (const float*)d_in[0];
    const float* w = (const float*)d_in[1];
    float* out = (float*)d_out;
    char* ws = (char*)d_ws;

    if (ws_size >= W2_NEED) {
        unsigned short* wtile = (unsigned short*)(ws + W2_WTILE);
        float* pm1 = (float*)(ws + W2_PM1);
        float* pm2 = (float*)(ws + W2_PM2);
        int*   pi1 = (int*)(ws + W2_PI1);
        int*   idx = (int*)(ws + W2_IDX);
        int*   cnt = (int*)(ws + W2_CNT);
        int*   list = (int*)(ws + W2_LIST);
        u16x8* zt = (u16x8*)d_out;     // z_q region doubles as zt scratch

        hipMemsetAsync(cnt, 0, 4, stream);
        zsplit_kernel<<<512, 256, 0, stream>>>(z, zt);
        wsplit_kernel<<<128, 256, 0, stream>>>(w, wtile);
        argmin2<<<512, 256, 0, stream>>>(zt, wtile, pm1, pm2, pi1);
        merge_kernel<<<64, 256, 0, stream>>>(pm1, pm2, pi1, idx, cnt, list);
        refine_kernel<<<128, 256, 0, stream>>>(z, w, cnt, list, idx);
        gather_kernel<<<BT / 8, 256, 0, stream>>>(w, idx, out);
    } else {
        float* inv  = (float*)(ws + WS_INV);
        float* wsq  = (float*)(ws + WS_WSQ);
        int*   idx  = (int*)(ws + WS_IDX);
        int*   cnt  = (int*)(ws + WS_CNT);
        int*   list = (int*)(ws + WS_LIST);

        hipMemsetAsync(cnt, 0, 4, stream);
        rownorm_kernel<<<BT / 4, 256, 0, stream>>>(z, BT, inv, 0);
        rownorm_kernel<<<NB / 4, 256, 0, stream>>>(w, NB, wsq, 1);
        argmin_mfma<<<BT / 64, 256, 0, stream>>>(z, w, inv, wsq, idx, cnt, list);
        refine_kernel<<<64, 256, 0, stream>>>(z, w, cnt, list, idx);
        gather_kernel<<<BT / 8, 256, 0, stream>>>(w, idx, out);
    }
}

// Round 7
// 643.818 us; speedup vs baseline: 3.5277x; 1.2205x over previous
//
#include <hip/hip_runtime.h>
#include <hip/hip_bf16.h>

#define BT 16384
#define NB 8192
#define DD 256
#define MARGIN 2e-4f

typedef short bf16x8 __attribute__((ext_vector_type(8)));
typedef unsigned short u16x8 __attribute__((ext_vector_type(8)));
typedef float f32x16 __attribute__((ext_vector_type(16)));
typedef __attribute__((address_space(1))) unsigned int gu32;
typedef __attribute__((address_space(3))) unsigned int lu32;

// ---- fast-path ws layout (bytes) ----
#define W2_WTILE 0
#define W2_PM1   (8*1024*1024)
#define W2_PM2   (W2_PM1 + 2*BT*4)
#define W2_PI1   (W2_PM2 + 2*BT*4)
#define W2_IDX   (W2_PI1 + 2*BT*4)
#define W2_CNT   (W2_IDX + BT*4)
#define W2_LIST  (W2_CNT + 256)
#define W2_NEED  ((size_t)(W2_LIST + BT*4))

// ---- fallback ws layout (round-4, validated) ----
#define WS_INV  0
#define WS_WSQ  (BT*4)
#define WS_IDX  (WS_WSQ + NB*4)
#define WS_CNT  (WS_IDX + BT*4)
#define WS_LIST (WS_CNT + 64)

__device__ __forceinline__ unsigned int f2bf(float f) {
    unsigned int u = __float_as_uint(f);
    return (u + 0x7FFFu + ((u >> 16) & 1u)) >> 16;
}

__device__ __forceinline__ void split8(const float4 a, const float4 b, u16x8 &hv, u16x8 &lv) {
    float xs[8] = {a.x, a.y, a.z, a.w, b.x, b.y, b.z, b.w};
    #pragma unroll
    for (int i = 0; i < 8; ++i) {
        unsigned int h = f2bf(xs[i]);
        hv[i] = (unsigned short)h;
        lv[i] = (unsigned short)f2bf(xs[i] - __uint_as_float(h << 16));
    }
}

// ================= FAST PATH =================

// Pre-split W: [ch 128][p 2][slot 32][code 64][8] bf16 (hi plane p=0, lo p=1)
__global__ void wsplit_kernel(const float* __restrict__ w,
                              unsigned short* __restrict__ wtile) {
    const int ch = blockIdx.x;
    const int t  = threadIdx.x;
    const int c  = t >> 2;
    const int q  = t & 3;
    const float* wr = w + (size_t)(ch * 64 + c) * DD + q * 64;
    unsigned short* base = wtile + (size_t)ch * 32768;
    #pragma unroll
    for (int g = 0; g < 8; ++g) {
        float4 v0 = reinterpret_cast<const float4*>(wr)[2 * g];
        float4 v1 = reinterpret_cast<const float4*>(wr)[2 * g + 1];
        u16x8 hv, lv;
        split8(v0, v1, hv, lv);
        const int slot = q * 8 + g;
        *reinterpret_cast<u16x8*>(base + ((size_t)slot * 64 + c) * 8) = hv;
        *reinterpret_cast<u16x8*>(base + ((size_t)(32 + slot) * 64 + c) * 8) = lv;
    }
}

// Pre-split z: normalize (f64 norm) + split, MFMA-fragment-major:
// zt[(rt*16+s)*64 + l] = row rt*32+(l&31), k = s*16+(l>>5)*8 .. +8
__global__ void zsplit_kernel(const float* __restrict__ z,
                              u16x8* __restrict__ zt) {
    __shared__ float inv_s[32];
    const int t = threadIdx.x;
    const int rt = blockIdx.x;
    {
        const int rl = t >> 3, sub = t & 7;
        const float4* zr = reinterpret_cast<const float4*>(
            z + (size_t)(rt * 32 + rl) * DD + sub * 32);
        double s = 0.0;
        #pragma unroll
        for (int i = 0; i < 8; ++i) {
            float4 v = zr[i];
            s += (double)v.x*v.x + (double)v.y*v.y + (double)v.z*v.z + (double)v.w*v.w;
        }
        s += __shfl_xor(s, 1, 64);
        s += __shfl_xor(s, 2, 64);
        s += __shfl_xor(s, 4, 64);
        if (sub == 0) {
            double n = sqrt(s);
            if (n < 1e-12) n = 1e-12;
            inv_s[rl] = (float)(1.0 / n);
        }
    }
    __syncthreads();
    const int sg = t >> 6, l = t & 63;
    const float inv = inv_s[l & 31];
    const int row = rt * 32 + (l & 31);
    #pragma unroll
    for (int si = 0; si < 4; ++si) {
        const int s = sg * 4 + si;
        const int k0 = s * 16 + (l >> 5) * 8;
        float4 a = *reinterpret_cast<const float4*>(z + (size_t)row * DD + k0);
        float4 b = *reinterpret_cast<const float4*>(z + (size_t)row * DD + k0 + 4);
        a.x *= inv; a.y *= inv; a.z *= inv; a.w *= inv;
        b.x *= inv; b.y *= inv; b.z *= inv; b.w *= inv;
        u16x8 hv, lv;
        split8(a, b, hv, lv);
        const size_t o = ((size_t)rt * 16 + s) * 64 + l;
        zt[o] = hv;
        zt[524288 + o] = lv;
    }
}

// Fused MFMA argmin: 256 blocks x 512 thr (8 waves = 2/SIMD).
// Block = 128 rows x one 4MB code-half. A in registers (asm-pinned),
// B double-buffered via global_load_lds with counted vmcnt.
__launch_bounds__(512, 2)
__global__ void argmin2(const u16x8* __restrict__ zt,
                        const unsigned short* __restrict__ wtile,
                        float* __restrict__ pm1,
                        float* __restrict__ pm2,
                        int* __restrict__ pi1) {
    __shared__ __align__(16) unsigned short Bbuf[2][2][32][64][8]; // 128 KB
    __shared__ float red_m1[2][128];
    __shared__ float red_m2[2][128];
    __shared__ int   red_i1[2][128];

    const int t = threadIdx.x, lane = t & 63, wv = t >> 6;
    const int wy = wv >> 1, wx = wv & 1;
    const int l5 = lane >> 5, lq = lane & 31;
    const int b = blockIdx.x;
    const int rb   = b >> 1;
    const int half = b & 1;                 // XCD parity -> each XCD on one 4MB half
    const int r0   = rb * 128;
    const int rt   = rb * 4 + wy;

    // ---- A-frags into registers, pinned against rematerialization ----
    const bf16x8* zhi = reinterpret_cast<const bf16x8*>(zt);
    bf16x8 ah[16], al[16];
    #pragma unroll
    for (int s = 0; s < 16; ++s) {
        const size_t o = ((size_t)rt * 16 + s) * 64 + lane;
        ah[s] = zhi[o];
        al[s] = zhi[524288 + o];
    }
    #pragma unroll
    for (int s = 0; s < 16; ++s) {
        asm volatile("" : "+v"(ah[s]));
        asm volatile("" : "+v"(al[s]));
    }

    float m1[16], m2[16]; int i1[16];
    #pragma unroll
    for (int r = 0; r < 16; ++r) { m1[r] = INFINITY; m2[r] = INFINITY; i1[r] = 0; }

    // staging: 512 thr x 8 x 16B = 64KB per chunk, linear copy
    const unsigned short* wsrc = wtile + (size_t)half * 2097152 + (size_t)t * 8;
    unsigned short* dst0 = &Bbuf[0][0][0][0][0] + (size_t)t * 8;
    unsigned short* dst1 = &Bbuf[1][0][0][0][0] + (size_t)t * 8;

    {   // prologue: chunk 0 -> buf 0
        #pragma unroll
        for (int i = 0; i < 8; ++i)
            __builtin_amdgcn_global_load_lds((gu32*)(wsrc + i * 4096),
                                             (lu32*)(dst0 + i * 4096), 16, 0, 0);
    }

    const int bn = wx * 32 + lq;
    int cur = 0;
    for (int ch = 0; ch < 64; ++ch) {
        if (ch < 63) {
            const unsigned short* src = wsrc + (size_t)(ch + 1) * 32768;
            unsigned short* dst = cur ? dst0 : dst1;
            #pragma unroll
            for (int i = 0; i < 8; ++i)
                __builtin_amdgcn_global_load_lds((gu32*)(src + i * 4096),
                                                 (lu32*)(dst + i * 4096), 16, 0, 0);
            asm volatile("s_waitcnt vmcnt(8)" ::: "memory");
        } else {
            asm volatile("s_waitcnt vmcnt(0)" ::: "memory");
        }
        __builtin_amdgcn_s_barrier();
        __builtin_amdgcn_sched_barrier(0);

        f32x16 acc0, acc1;
        #pragma unroll
        for (int r = 0; r < 16; ++r) { acc0[r] = 0.f; acc1[r] = 0.f; }

        #pragma unroll
        for (int s = 0; s < 16; ++s) {
            const int sl = 2 * s + l5;
            bf16x8 bh = *reinterpret_cast<const bf16x8*>(&Bbuf[cur][0][sl][bn][0]);
            bf16x8 bl = *reinterpret_cast<const bf16x8*>(&Bbuf[cur][1][sl][bn][0]);
            acc0 = __builtin_amdgcn_mfma_f32_32x32x16_bf16(ah[s], bh, acc0, 0, 0, 0);
            acc1 = __builtin_amdgcn_mfma_f32_32x32x16_bf16(ah[s], bl, acc1, 0, 0, 0);
            acc1 = __builtin_amdgcn_mfma_f32_32x32x16_bf16(al[s], bh, acc1, 0, 0, 0);
        }

        const int nidx = half * 4096 + ch * 64 + bn;
        #pragma unroll
        for (int r = 0; r < 16; ++r) {
            float v = -2.0f * (acc0[r] + acc1[r]);   // ||w||^2==1: rank by -2dot
            if (v < m1[r]) { m2[r] = m1[r]; m1[r] = v; i1[r] = nidx; }
            else if (v < m2[r]) m2[r] = v;
        }

        __builtin_amdgcn_sched_barrier(0);
        __builtin_amdgcn_s_barrier();
        cur ^= 1;
    }

    // reduce across 32 code-lanes (ties -> smaller index)
    #pragma unroll
    for (int off = 1; off < 32; off <<= 1) {
        #pragma unroll
        for (int r = 0; r < 16; ++r) {
            float om1 = __shfl_xor(m1[r], off, 64);
            float om2 = __shfl_xor(m2[r], off, 64);
            int   oi  = __shfl_xor(i1[r], off, 64);
            if (om1 < m1[r] || (om1 == m1[r] && oi < i1[r])) {
                m2[r] = fminf(m1[r], om2); m1[r] = om1; i1[r] = oi;
            } else {
                m2[r] = fminf(om1, m2[r]);
            }
        }
    }
    if (lq == 0) {
        #pragma unroll
        for (int r = 0; r < 16; ++r) {
            int ml = wy * 32 + (r & 3) + 8 * (r >> 2) + 4 * l5;
            red_m1[wx][ml] = m1[r];
            red_m2[wx][ml] = m2[r];
            red_i1[wx][ml] = i1[r];
        }
    }
    __syncthreads();
    if (t < 128) {
        float a1 = red_m1[0][t], a2 = red_m2[0][t]; int ai = red_i1[0][t];
        float b1 = red_m1[1][t], b2 = red_m2[1][t]; int bi = red_i1[1][t];
        float f1, f2; int fi;
        if (b1 < a1 || (b1 == a1 && bi < ai)) { f1 = b1; fi = bi; f2 = fminf(a1, b2); }
        else                                  { f1 = a1; fi = ai; f2 = fminf(b1, a2); }
        pm1[half * BT + r0 + t] = f1;
        pm2[half * BT + r0 + t] = f2;
        pi1[half * BT + r0 + t] = fi;
    }
}

// merge the two code-halves per row; flag near-ties for refine
__global__ void merge_kernel(const float* __restrict__ pm1,
                             const float* __restrict__ pm2,
                             const int* __restrict__ pi1,
                             int* __restrict__ idx_out,
                             int* __restrict__ counter,
                             int* __restrict__ list) {
    const int r = blockIdx.x * 256 + threadIdx.x;
    float a1 = pm1[r], a2 = pm2[r]; int ai = pi1[r];
    float b1 = pm1[BT + r], b2 = pm2[BT + r]; int bi = pi1[BT + r];
    float f1, f2; int fi;
    if (b1 < a1 || (b1 == a1 && bi < ai)) { f1 = b1; fi = bi; f2 = fminf(a1, b2); }
    else                                  { f1 = a1; fi = ai; f2 = fminf(b1, a2); }
    idx_out[r] = fi;
    if (f2 - f1 < MARGIN) {
        int p = atomicAdd(counter, 1);
        list[p] = r;
    }
}

// ================= SHARED (refine / gather) =================

__global__ void refine_kernel(const float* __restrict__ z,
                              const float* __restrict__ w,
                              const int* __restrict__ counter,
                              const int* __restrict__ list,
                              int* __restrict__ idx_out) {
    __shared__ double zn_s[256];
    __shared__ double rv[256];
    __shared__ int    ri[256];
    const int t = threadIdx.x;
    const int cnt = *counter;
    for (int item = blockIdx.x; item < cnt; item += gridDim.x) {
        const int row = list[item];
        double zv = (double)z[(size_t)row * DD + t];
        __syncthreads();
        rv[t] = zv * zv;
        __syncthreads();
        for (int s = 128; s; s >>= 1) { if (t < s) rv[t] += rv[t + s]; __syncthreads(); }
        double norm = sqrt(rv[0]);
        if (norm < 1e-12) norm = 1e-12;
        __syncthreads();
        zn_s[t] = zv / norm;
        __syncthreads();
        double bv = INFINITY; int bi = 0;
        for (int n = t; n < NB; n += 256) {
            double dot = 0.0, wsqd = 0.0;
            const float* wr = w + (size_t)n * DD;
            for (int k = 0; k < DD; ++k) {
                double wv = (double)wr[k];
                dot  += zn_s[k] * wv;
                wsqd += wv * wv;
            }
            double dist = wsqd - 2.0 * dot;
            if (dist < bv) { bv = dist; bi = n; }
        }
        __syncthreads();
        rv[t] = bv; ri[t] = bi;
        __syncthreads();
        for (int s = 128; s; s >>= 1) {
            if (t < s) {
                if (rv[t + s] < rv[t] || (rv[t + s] == rv[t] && ri[t + s] < ri[t])) {
                    rv[t] = rv[t + s]; ri[t] = ri[t + s];
                }
            }
            __syncthreads();
        }
        if (t == 0) idx_out[row] = ri[0];
        __syncthreads();
    }
}

__global__ void gather_kernel(const float* __restrict__ w,
                              const int* __restrict__ idx,
                              float* __restrict__ out) {
    const int t = threadIdx.x;
    const int blk = blockIdx.x;
    const int row = blk * 8 + (t >> 5);
    const int lane = t & 31;
    int n = idx[row];
    if ((unsigned)n >= (unsigned)NB) n = 0;
    const float4* src = reinterpret_cast<const float4*>(w + (size_t)n * DD + lane * 8);
    float4 v0 = src[0], v1 = src[1];
    float4* dst = reinterpret_cast<float4*>(out + (size_t)row * DD + lane * 8);
    dst[0] = v0;
    dst[1] = v1;
    if (t < 8) {
        int r2 = blk * 8 + t;
        out[(size_t)BT * DD + r2] = (float)idx[r2];
    }
}

// ================= FALLBACK (round-4, validated) =================

__global__ void rownorm_kernel(const float* __restrict__ x, int rows,
                               float* __restrict__ out, int mode) {
    int row  = blockIdx.x * 4 + (threadIdx.x >> 6);
    int lane = threadIdx.x & 63;
    if (row >= rows) return;
    const float4 v = *reinterpret_cast<const float4*>(x + (size_t)row * DD + lane * 4);
    double s = (double)v.x * v.x + (double)v.y * v.y + (double)v.z * v.z + (double)v.w * v.w;
    #pragma unroll
    for (int off = 32; off; off >>= 1) s += __shfl_down(s, off, 64);
    if (lane == 0) {
        if (mode == 0) {
            double n = sqrt(s);
            if (n < 1e-12) n = 1e-12;
            out[row] = (float)(1.0 / n);
        } else {
            out[row] = (float)s;
        }
    }
}

__launch_bounds__(256, 1)
__global__ void argmin_mfma(const float* __restrict__ z,
                            const float* __restrict__ w,
                            const float* __restrict__ invn,
                            const float* __restrict__ wsq,
                            int* __restrict__ idx_out,
                            int* __restrict__ counter,
                            int* __restrict__ list) {
    __shared__ unsigned short Ahi[64][256];
    __shared__ unsigned short Alo[64][256];
    __shared__ unsigned short Bhi[64][256];
    __shared__ unsigned short Blo[64][256];
    __shared__ float wsq_s[64];
    __shared__ float red_m1[2][64];
    __shared__ float red_m2[2][64];
    __shared__ int   red_i1[2][64];

    const int t    = threadIdx.x;
    const int lane = t & 63;
    const int wv   = t >> 6;
    const int wy = wv >> 1, wx = wv & 1;
    const int l5 = lane >> 5, lq = lane & 31;
    const int r0 = blockIdx.x * 64;

    {
        const int ar = t >> 2;
        const int sbase = (t & 3) * 8;
        const float* zr = z + (size_t)(r0 + ar) * DD + (t & 3) * 64;
        #pragma unroll
        for (int g = 0; g < 8; ++g) {
            float4 v0 = reinterpret_cast<const float4*>(zr)[2 * g];
            float4 v1 = reinterpret_cast<const float4*>(zr)[2 * g + 1];
            u16x8 hv, lv;
            split8(v0, v1, hv, lv);
            int slot = (sbase + g) ^ (ar & 7);
            *reinterpret_cast<u16x8*>(&Ahi[ar][slot * 8]) = hv;
            *reinterpret_cast<u16x8*>(&Alo[ar][slot * 8]) = lv;
        }
    }

    float twoinv[16];
    #pragma unroll
    for (int r = 0; r < 16; ++r)
        twoinv[r] = 2.0f * invn[r0 + wy * 32 + (r & 3) + 8 * (r >> 2) + 4 * l5];

    float m1[16], m2[16]; int i1[16];
    #pragma unroll
    for (int r = 0; r < 16; ++r) { m1[r] = INFINITY; m2[r] = INFINITY; i1[r] = 0; }

    const int cc = t >> 2;
    const int sbase = (t & 3) * 8;
    float4 pre[16];
    {
        const float* wb = w + (size_t)cc * DD + (t & 3) * 64;
        #pragma unroll
        for (int q = 0; q < 16; ++q) pre[q] = reinterpret_cast<const float4*>(wb)[q];
    }
    float wsq_pre = (t < 64) ? wsq[t] : 0.f;

    const int am = wy * 32 + lq;
    const int bn = wx * 32 + lq;
    const int sxor = lq & 7;

    for (int ch = 0; ch < 128; ++ch) {
        __syncthreads();
        #pragma unroll
        for (int g = 0; g < 8; ++g) {
            u16x8 hv, lv;
            split8(pre[2 * g], pre[2 * g + 1], hv, lv);
            int slot = (sbase + g) ^ (cc & 7);
            *reinterpret_cast<u16x8*>(&Bhi[cc][slot * 8]) = hv;
            *reinterpret_cast<u16x8*>(&Blo[cc][slot * 8]) = lv;
        }
        if (t < 64) wsq_s[t] = wsq_pre;
        __syncthreads();

        if (ch < 127) {
            const float* wb = w + (size_t)((ch + 1) * 64 + cc) * DD + (t & 3) * 64;
            #pragma unroll
            for (int q = 0; q < 16; ++q) pre[q] = reinterpret_cast<const float4*>(wb)[q];
            if (t < 64) wsq_pre = wsq[(ch + 1) * 64 + t];
        }

        f32x16 acc0, acc1;
        #pragma unroll
        for (int r = 0; r < 16; ++r) { acc0[r] = 0.f; acc1[r] = 0.f; }

        #pragma unroll
        for (int s = 0; s < 16; ++s) {
            const int sl = (2 * s + l5) ^ sxor;
            bf16x8 ah = *reinterpret_cast<const bf16x8*>(&Ahi[am][sl * 8]);
            bf16x8 al = *reinterpret_cast<const bf16x8*>(&Alo[am][sl * 8]);
            bf16x8 bh = *reinterpret_cast<const bf16x8*>(&Bhi[bn][sl * 8]);
            bf16x8 bl = *reinterpret_cast<const bf16x8*>(&Blo[bn][sl * 8]);
            acc0 = __builtin_amdgcn_mfma_f32_32x32x16_bf16(ah, bh, acc0, 0, 0, 0);
            acc1 = __builtin_amdgcn_mfma_f32_32x32x16_bf16(ah, bl, acc1, 0, 0, 0);
            acc0 = __builtin_amdgcn_mfma_f32_32x32x16_bf16(al, bh, acc0, 0, 0, 0);
        }

        const float wq = wsq_s[bn];
        const int nidx = ch * 64 + bn;
        #pragma unroll
        for (int r = 0; r < 16; ++r) {
            float v = wq - twoinv[r] * (acc0[r] + acc1[r]);
            if (v < m1[r]) { m2[r] = m1[r]; m1[r] = v; i1[r] = nidx; }
            else if (v < m2[r]) m2[r] = v;
        }
    }

    #pragma unroll
    for (int off = 1; off < 32; off <<= 1) {
        #pragma unroll
        for (int r = 0; r < 16; ++r) {
            float om1 = __shfl_xor(m1[r], off, 64);
            float om2 = __shfl_xor(m2[r], off, 64);
            int   oi  = __shfl_xor(i1[r], off, 64);
            if (om1 < m1[r] || (om1 == m1[r] && oi < i1[r])) {
                m2[r] = fminf(m1[r], om2); m1[r] = om1; i1[r] = oi;
            } else {
                m2[r] = fminf(om1, m2[r]);
            }
        }
    }
    if (lq == 0) {
        #pragma unroll
        for (int r = 0; r < 16; ++r) {
            int ml = wy * 32 + (r & 3) + 8 * (r >> 2) + 4 * l5;
            red_m1[wx][ml] = m1[r];
            red_m2[wx][ml] = m2[r];
            red_i1[wx][ml] = i1[r];
        }
    }
    __syncthreads();
    if (t < 64) {
        float a1 = red_m1[0][t], a2 = red_m2[0][t]; int ai = red_i1[0][t];
        float b1 = red_m1[1][t], b2 = red_m2[1][t]; int bi = red_i1[1][t];
        float f1, f2; int fi;
        if (b1 < a1 || (b1 == a1 && bi < ai)) { f1 = b1; fi = bi; f2 = fminf(a1, b2); }
        else                                  { f1 = a1; fi = ai; f2 = fminf(b1, a2); }
        idx_out[r0 + t] = fi;
        if (f2 - f1 < MARGIN) {
            int p = atomicAdd(counter, 1);
            list[p] = r0 + t;
        }
    }
}

extern "C" void kernel_launch(void* const* d_in, const int* in_sizes, int n_in,
                              void* d_out, int out_size, void* d_ws, size_t ws_size,
                              hipStream_t stream) {
    const float* z = (const float*)d_in[0];
    const float* w = (const float*)d_in[1];
    float* out = (float*)d_out;
    char* ws = (char*)d_ws;

    if (ws_size >= W2_NEED) {
        unsigned short* wtile = (unsigned short*)(ws + W2_WTILE);
        float* pm1 = (float*)(ws + W2_PM1);
        float* pm2 = (float*)(ws + W2_PM2);
        int*   pi1 = (int*)(ws + W2_PI1);
        int*   idx = (int*)(ws + W2_IDX);
        int*   cnt = (int*)(ws + W2_CNT);
        int*   list = (int*)(ws + W2_LIST);
        u16x8* zt = (u16x8*)d_out;     // z_q region doubles as zt scratch

        hipMemsetAsync(cnt, 0, 4, stream);
        zsplit_kernel<<<512, 256, 0, stream>>>(z, zt);
        wsplit_kernel<<<128, 256, 0, stream>>>(w, wtile);
        argmin2<<<256, 512, 0, stream>>>(zt, wtile, pm1, pm2, pi1);
        merge_kernel<<<64, 256, 0, stream>>>(pm1, pm2, pi1, idx, cnt, list);
        refine_kernel<<<128, 256, 0, stream>>>(z, w, cnt, list, idx);
        gather_kernel<<<BT / 8, 256, 0, stream>>>(w, idx, out);
    } else {
        float* inv  = (float*)(ws + WS_INV);
        float* wsq  = (float*)(ws + WS_WSQ);
        int*   idx  = (int*)(ws + WS_IDX);
        int*   cnt  = (int*)(ws + WS_CNT);
        int*   list = (int*)(ws + WS_LIST);

        hipMemsetAsync(cnt, 0, 4, stream);
        rownorm_kernel<<<BT / 4, 256, 0, stream>>>(z, BT, inv, 0);
        rownorm_kernel<<<NB / 4, 256, 0, stream>>>(w, NB, wsq, 1);
        argmin_mfma<<<BT / 64, 256, 0, stream>>>(z, w, inv, wsq, idx, cnt, list);
        refine_kernel<<<64, 256, 0, stream>>>(z, w, cnt, list, idx);
        gather_kernel<<<BT / 8, 256, 0, stream>>>(w, idx, out);
    }
}